// Round 1
// baseline (364.514 us; speedup 1.0000x reference)
//
#include <hip/hip_runtime.h>

typedef __bf16 bf16x8 __attribute__((ext_vector_type(8)));
typedef float f32x4 __attribute__((ext_vector_type(4)));
typedef float f32x16 __attribute__((ext_vector_type(16)));
typedef unsigned short u16;
typedef unsigned int u32;
typedef u16 u16x4 __attribute__((ext_vector_type(4)));
typedef u32 u32x4 __attribute__((ext_vector_type(4)));

__device__ __forceinline__ u16 f2bf(float f) {
    union { float f; u32 u; } x{f};
    u32 r = x.u + 0x7FFFu + ((x.u >> 16) & 1u);  // RNE
    return (u16)(r >> 16);
}

__device__ __forceinline__ float ex2(float x) {
#if __has_builtin(__builtin_amdgcn_exp2f)
    return __builtin_amdgcn_exp2f(x);
#else
    return __expf(x * 0.6931471805599453f);
#endif
}

// round-half-up bf16 (inputs >= 0), packed pair into u32
__device__ __forceinline__ u32 pkbf(float a, float b) {
    union { float f; u32 u; } ca{a}, cb{b};
    return ((ca.u + 0x8000u) >> 16) | (((cb.u + 0x8000u) >> 16) << 16);
}

// async global->LDS, 16B per lane; LDS dest = wave-uniform base + lane*16
#define GLD16(g, l)                                                            \
    __builtin_amdgcn_global_load_lds(                                          \
        (const __attribute__((address_space(1))) u32*)(g),                     \
        (__attribute__((address_space(3))) u32*)(l), 16, 0, 0)

// ---------------------------------------------------------------------------
// Elementwise fp32 -> bf16 convert (x)
// ---------------------------------------------------------------------------
__global__ void convert_bf16(const float* __restrict__ src, u16* __restrict__ dst, int n4) {
    int i = blockIdx.x * blockDim.x + threadIdx.x;
    if (i < n4) {
        float4 f = *(const float4*)(src + (size_t)i * 4);
        u16x4 u = { f2bf(f.x), f2bf(f.y), f2bf(f.z), f2bf(f.w) };
        *(u16x4*)(dst + (size_t)i * 4) = u;
    }
}

// ---------------------------------------------------------------------------
// Both weight transposes in one kernel.
// ---------------------------------------------------------------------------
__global__ __launch_bounds__(256) void prep_weights(
    const float* __restrict__ wq, const float* __restrict__ wp,
    u16* __restrict__ WqT, u16* __restrict__ WpT)
{
    __shared__ u16 tile[32][33];
    int id = blockIdx.x;
    const float* src; u16* dst; int R, C, bx, by;
    if (id < 1728) { src = wq; dst = WqT; R = 768; C = 2304; bx = (id % 72) * 32; by = (id / 72) * 32; }
    else { id -= 1728; src = wp; dst = WpT; R = 768; C = 768; bx = (id % 24) * 32; by = (id / 24) * 32; }
    int x = threadIdx.x & 31, y = threadIdx.x >> 5;
    #pragma unroll
    for (int i = 0; i < 32; i += 8)
        tile[y + i][x] = f2bf(src[(size_t)(by + y + i) * C + bx + x]);
    __syncthreads();
    #pragma unroll
    for (int i = 0; i < 32; i += 8)
        dst[(size_t)(bx + y + i) * R + by + x] = tile[x][y + i];
}

// ---------------------------------------------------------------------------
// QKV GEMM, 8-phase 256x256 schedule (T1+T2-equiv+T3+T4+T5):
//   - 512 threads = 8 waves (2M x 4N), per-wave 128x64 output, BK=64
//   - 128 KiB dynamic LDS: A[2][256][64], B[2][256][64], granule-XOR swizzle
//     (verified conflict-free: SQ_LDS_BANK_CONFLICT==0 in predecessor)
//   - 4 phases per K-tile, raw s_barrier (no vmcnt drain), counted
//     s_waitcnt vmcnt(4) once per K-tile; staging stream: B-halves of tile
//     t+1 at phases 1-2 (other buffer), A-halves of tile t+2 at phases 3-4
//     (this buffer, legal: all reads retired by phase-2 lgkmcnt(0)+barrier)
//   - V-section (bn>=1536, tile-aligned) swaps MFMA operands, scatters to Vt
// ---------------------------------------------------------------------------
#define QUAD(AF, BF, I0)                                                       \
    if (!vsec) {                                                               \
        _Pragma("unroll") for (int i = 0; i < 4; i++)                          \
        _Pragma("unroll") for (int n = 0; n < 4; n++)                          \
            acc[(I0) + i][n] = __builtin_amdgcn_mfma_f32_16x16x32_bf16(        \
                AF[(I0) + i], BF[n], acc[(I0) + i][n], 0, 0, 0);               \
    } else {                                                                   \
        _Pragma("unroll") for (int i = 0; i < 4; i++)                          \
        _Pragma("unroll") for (int n = 0; n < 4; n++)                          \
            acc[(I0) + i][n] = __builtin_amdgcn_mfma_f32_16x16x32_bf16(        \
                BF[n], AF[(I0) + i], acc[(I0) + i][n], 0, 0, 0);               \
    }

#define STAGE_A8(tile, hh)                                                     \
    { const u16* g_ = Ap + (size_t)((hh) * 128) * K + (tile) * 64;             \
      u16* d_ = ldsA + ((tile) & 1) * 16384 + ((hh) * 128 + wave * 16) * 64;   \
      GLD16(g_,         d_);                                                   \
      GLD16(g_ + 8 * K, d_ + 8 * 64); }

#define STAGE_B8(tile, hh)                                                     \
    { const u16* g_ = Bp + (size_t)((hh) * 128) * K + (tile) * 64;             \
      u16* d_ = ldsB + ((tile) & 1) * 16384 + ((hh) * 128 + wave * 16) * 64;   \
      GLD16(g_,         d_);                                                   \
      GLD16(g_ + 8 * K, d_ + 8 * 64); }

template <int K>
__global__ __launch_bounds__(512, 2) void gemm_qkv8(
    const u16* __restrict__ A,
    const u16* __restrict__ Wt,
    u16* __restrict__ QKV,
    u16* __restrict__ Vt,
    float qscale)
{
    extern __shared__ __align__(16) u16 lds[];   // 128 KiB total

    constexpr int NT = K / 64;                    // 12 K-tiles
    int tid = threadIdx.x;
    int wave = tid >> 6, lane = tid & 63;
    int quad = lane >> 4, l16 = lane & 15;
    int wm = (wave >> 2) * 128, wn = (wave & 3) * 64;

    // bijective XCD swizzle: 288 blocks = 8 XCDs x 36
    int id = blockIdx.x;
    int lin = (id & 7) * 36 + (id >> 3);
    int bm = (lin / 9) * 256;
    int bn = (lin % 9) * 256;
    bool vsec = (bn >= 1536);                     // tiles 6..8 are pure V

    f32x4 acc[8][4] = {};

    int srow = lane >> 3;
    int scg = (lane & 7) ^ srow;
    const u16* Ap = A  + (size_t)(bm + wave * 16 + srow) * K + scg * 8;
    const u16* Bp = Wt + (size_t)(bn + wave * 16 + srow) * K + scg * 8;

    int fg0 = ((0 * 4 + quad) ^ (l16 & 7)) * 8;
    int fg1 = ((1 * 4 + quad) ^ (l16 & 7)) * 8;

    u16* ldsA = lds;           // 2 x 16384 u16
    u16* ldsB = lds + 32768;   // 2 x 16384 u16

    // prologue: tile0 fully, tile1 A-halves (12 loads/thread); wait tile0 (4 left)
    STAGE_A8(0, 0); STAGE_A8(0, 1); STAGE_B8(0, 0); STAGE_B8(0, 1);
    STAGE_A8(1, 0); STAGE_A8(1, 1);
    asm volatile("s_waitcnt vmcnt(4)" ::: "memory");
    __builtin_amdgcn_s_barrier();

    #pragma unroll 2
    for (int t = 0; t < NT; ++t) {
        const u16* As = ldsA + (t & 1) * 16384;
        const u16* Bs = ldsB + (t & 1) * 16384;

        bf16x8 a0[8], a1[8], b0[4], b1[4];

        // ---- phase 1: read h0 frags; stage B0(t+1) -> other buffer ----
        #pragma unroll
        for (int n = 0; n < 4; n++)
            b0[n] = *(const bf16x8*)&Bs[(wn + n * 16 + l16) * 64 + fg0];
        #pragma unroll
        for (int i = 0; i < 8; i++)
            a0[i] = *(const bf16x8*)&As[(wm + i * 16 + l16) * 64 + fg0];
        if (t + 1 < NT) STAGE_B8(t + 1, 0);
        __builtin_amdgcn_s_barrier();
        __builtin_amdgcn_s_setprio(1);
        QUAD(a0, b0, 0);
        __builtin_amdgcn_s_setprio(0);
        __builtin_amdgcn_s_barrier();

        // ---- phase 2: read h1 frags; stage B1(t+1); retire ALL buf reads ----
        #pragma unroll
        for (int n = 0; n < 4; n++)
            b1[n] = *(const bf16x8*)&Bs[(wn + n * 16 + l16) * 64 + fg1];
        #pragma unroll
        for (int i = 0; i < 8; i++)
            a1[i] = *(const bf16x8*)&As[(wm + i * 16 + l16) * 64 + fg1];
        if (t + 1 < NT) STAGE_B8(t + 1, 1);
        __builtin_amdgcn_s_barrier();
        __builtin_amdgcn_s_setprio(1);
        QUAD(a0, b0, 4);
        __builtin_amdgcn_s_setprio(0);
        asm volatile("s_waitcnt lgkmcnt(0)" ::: "memory");  // no in-flight buf reads past here
        __builtin_amdgcn_s_barrier();
        __builtin_amdgcn_sched_barrier(0);

        // ---- phase 3: stage A0(t+2) -> THIS buffer (reads all retired) ----
        if (t + 2 < NT) STAGE_A8(t + 2, 0);
        __builtin_amdgcn_s_barrier();
        __builtin_amdgcn_s_setprio(1);
        QUAD(a1, b1, 0);
        __builtin_amdgcn_s_setprio(0);
        __builtin_amdgcn_s_barrier();
        __builtin_amdgcn_sched_barrier(0);

        // ---- phase 4: stage A1(t+2); counted vmcnt (never 0 in steady state) ----
        if (t + 2 < NT) STAGE_A8(t + 2, 1);
        __builtin_amdgcn_s_barrier();
        __builtin_amdgcn_s_setprio(1);
        QUAD(a1, b1, 4);
        __builtin_amdgcn_s_setprio(0);
        if (t + 1 < NT) {
            if (t + 2 < NT) { asm volatile("s_waitcnt vmcnt(4)" ::: "memory"); }
            else            { asm volatile("s_waitcnt vmcnt(0)" ::: "memory"); }
        }
        __builtin_amdgcn_s_barrier();
    }

    if (!vsec) {
        float sc = (bn < 768) ? qscale : 1.0f;   // Q tiles 0..2, K tiles 3..5
        #pragma unroll
        for (int i = 0; i < 8; i++) {
            #pragma unroll
            for (int n = 0; n < 4; n++) {
                #pragma unroll
                for (int rg = 0; rg < 4; rg++) {
                    int row = bm + wm + i * 16 + quad * 4 + rg;
                    int col = bn + wn + n * 16 + l16;
                    QKV[(size_t)row * 2304 + col] = f2bf(acc[i][n][rg] * sc);
                }
            }
        }
    } else {
        #pragma unroll
        for (int i = 0; i < 8; i++) {
            #pragma unroll
            for (int n = 0; n < 4; n++) {
                #pragma unroll
                for (int rg = 0; rg < 4; rg++) {
                    int d = (bn - 1536) + wn + n * 16 + quad * 4 + rg;
                    int ng = bm + wm + i * 16 + l16;
                    int b = ng >> 10, nn = ng & 1023, h = d >> 6;
                    Vt[((size_t)(b * 12 + h) * 64 + (d & 63)) * 1024 + nn] = f2bf(acc[i][n][rg]);
                }
            }
        }
    }
}

// ---------------------------------------------------------------------------
// Output projection GEMM (unchanged).
// ---------------------------------------------------------------------------
template <int K>
__global__ __launch_bounds__(256) void gemm_proj(
    const u16* __restrict__ A,
    const u16* __restrict__ Bt,
    float* __restrict__ Cp,
    const float* __restrict__ bias,
    int M, int N)
{
    __shared__ __align__(16) u16 As[128 * 64];
    __shared__ __align__(16) u16 Bs[128 * 64];

    int tid = threadIdx.x;
    int wave = tid >> 6, lane = tid & 63;
    int quad = lane >> 4, l16 = lane & 15;
    int wm = (wave >> 1) * 64, wn = (wave & 1) * 64;
    int bm = blockIdx.y * 128, bn = blockIdx.x * 128;

    f32x4 acc[4][4] = {};

    int srow = lane >> 3;
    int scg = ((lane & 7) ^ srow) * 8;
    const u16* Ap = A + (size_t)(bm + wave * 32 + srow) * K + scg;
    const u16* Bp = Bt + (size_t)(bn + wave * 32 + srow) * K + scg;

    int fg0 = (((0 * 4 + quad) ^ (l16 & 7)) * 8);
    int fg1 = (((1 * 4 + quad) ^ (l16 & 7)) * 8);

    for (int k0 = 0; k0 < K; k0 += 64) {
        #pragma unroll
        for (int j = 0; j < 4; j++) {
            GLD16(Ap + k0 + (size_t)j * 8 * K, &As[(wave * 32 + j * 8) * 64]);
            GLD16(Bp + k0 + (size_t)j * 8 * K, &Bs[(wave * 32 + j * 8) * 64]);
        }
        __syncthreads();

        #pragma unroll
        for (int h = 0; h < 2; h++) {
            int fg = h ? fg1 : fg0;
            bf16x8 af[4], bfr[4];
            #pragma unroll
            for (int i = 0; i < 4; i++) {
                af[i]  = *(const bf16x8*)&As[(wm + i * 16 + l16) * 64 + fg];
                bfr[i] = *(const bf16x8*)&Bs[(wn + i * 16 + l16) * 64 + fg];
            }
            #pragma unroll
            for (int mi = 0; mi < 4; mi++)
                #pragma unroll
                for (int ni = 0; ni < 4; ni++)
                    acc[mi][ni] = __builtin_amdgcn_mfma_f32_16x16x32_bf16(af[mi], bfr[ni], acc[mi][ni], 0, 0, 0);
        }
        __syncthreads();
    }

    #pragma unroll
    for (int mi = 0; mi < 4; mi++) {
        #pragma unroll
        for (int ni = 0; ni < 4; ni++) {
            #pragma unroll
            for (int rg = 0; rg < 4; rg++) {
                int row = bm + wm + mi * 16 + quad * 4 + rg;
                int col = bn + wn + ni * 16 + l16;
                Cp[(size_t)row * N + col] = acc[mi][ni][rg] + bias[col];
            }
        }
    }
}

// ---------------------------------------------------------------------------
// Flash attention v4 (unchanged): 32x32x16 MFMA, no P LDS roundtrip.
// ---------------------------------------------------------------------------
__global__ __launch_bounds__(256, 4) void attn_kernel(
    const u16* __restrict__ qkv,
    const u16* __restrict__ Vt,
    u16* __restrict__ ctx)
{
    __shared__ __align__(16) u16 Ks[2][4096];   // 2 x 64key x 64d (swizzled)
    __shared__ __align__(16) u16 Vs[2][4096];   // 2 x 64d x 64key (swizzled)

    int qt = blockIdx.x;            // 0..7 (128 q rows per block)
    int bh = blockIdx.y;            // 0..95
    int b = bh / 12, h = bh % 12;
    int tid = threadIdx.x;
    int wave = tid >> 6, lane = tid & 63;
    int l32 = lane & 31, half = lane >> 5;

    const u16* qbase = qkv + (size_t)(b * 1024 + qt * 128 + wave * 32 + l32) * 2304 + h * 64;
    bf16x8 qa[4];
    #pragma unroll
    for (int ks = 0; ks < 4; ks++)
        qa[ks] = *(const bf16x8*)(qbase + ks * 16 + half * 8);

    int srow = lane >> 3;
    int scol = (lane & 7) ^ srow;
    const u16* kA = qkv + (size_t)(b * 1024 + wave * 16 + srow) * 2304 + 768 + h * 64 + scol * 8;
    const u16* vA = Vt + ((size_t)bh * 64 + wave * 16 + srow) * 1024 + scol * 8;

    bf16x8 ones;
    #pragma unroll
    for (int j = 0; j < 8; j++) ((u16*)&ones)[j] = 0x3F80;  // bf16 1.0

    f32x16 o0 = {}, o1 = {}, lsum = {};

    int fgo[4];
    #pragma unroll
    for (int ks = 0; ks < 4; ks++)
        fgo[ks] = (((ks * 2 + half) ^ (lane & 7)) * 8);

    {
        GLD16(kA,            &Ks[0][(wave * 2 + 0) * 512]);
        GLD16(kA + 8 * 2304, &Ks[0][(wave * 2 + 1) * 512]);
        GLD16(vA,            &Vs[0][(wave * 2 + 0) * 512]);
        GLD16(vA + 8 * 1024, &Vs[0][(wave * 2 + 1) * 512]);
    }

    #pragma unroll 2
    for (int kt = 0; kt < 16; kt++) {
        int buf = kt & 1;
        __syncthreads();   // drains vmcnt(0): buf is populated

        if (kt < 15) {
            const u16* k0 = kA + (size_t)(kt + 1) * (64 * 2304);
            const u16* v0 = vA + (size_t)(kt + 1) * 64;
            GLD16(k0,            &Ks[buf ^ 1][(wave * 2 + 0) * 512]);
            GLD16(k0 + 8 * 2304, &Ks[buf ^ 1][(wave * 2 + 1) * 512]);
            GLD16(v0,            &Vs[buf ^ 1][(wave * 2 + 0) * 512]);
            GLD16(v0 + 8 * 1024, &Vs[buf ^ 1][(wave * 2 + 1) * 512]);
        }

        f32x16 st0 = {}, st1 = {};
        #pragma unroll
        for (int ks = 0; ks < 4; ks++) {
            bf16x8 kf0 = *(const bf16x8*)&Ks[buf][(l32)      * 64 + fgo[ks]];
            bf16x8 kf1 = *(const bf16x8*)&Ks[buf][(32 + l32) * 64 + fgo[ks]];
            st0 = __builtin_amdgcn_mfma_f32_32x32x16_bf16(kf0, qa[ks], st0, 0, 0, 0);
            st1 = __builtin_amdgcn_mfma_f32_32x32x16_bf16(kf1, qa[ks], st1, 0, 0, 0);
        }

        bf16x8 pf[4];
        #pragma unroll
        for (int t = 0; t < 2; t++) {
            u32 pk[8];
            #pragma unroll
            for (int g = 0; g < 4; g++) {
                float p0 = ex2(t ? st1[4 * g + 0] : st0[4 * g + 0]);
                float p1 = ex2(t ? st1[4 * g + 1] : st0[4 * g + 1]);
                float p2 = ex2(t ? st1[4 * g + 2] : st0[4 * g + 2]);
                float p3 = ex2(t ? st1[4 * g + 3] : st0[4 * g + 3]);
                pk[2 * g + 0] = pkbf(p0, p1);
                pk[2 * g + 1] = pkbf(p2, p3);
            }
            u32 rA0 = __shfl_xor(half ? pk[0] : pk[2], 32);
            u32 rA1 = __shfl_xor(half ? pk[1] : pk[3], 32);
            u32 rB0 = __shfl_xor(half ? pk[4] : pk[6], 32);
            u32 rB1 = __shfl_xor(half ? pk[5] : pk[7], 32);
            u32x4 f0 = { half ? rA0 : pk[0], half ? rA1 : pk[1],
                         half ? pk[2] : rA0, half ? pk[3] : rA1 };
            u32x4 f1 = { half ? rB0 : pk[4], half ? rB1 : pk[5],
                         half ? pk[6] : rB0, half ? pk[7] : rB1 };
            union { u32x4 u; bf16x8 b; } c0{f0}, c1{f1};
            pf[2 * t + 0] = c0.b;
            pf[2 * t + 1] = c1.b;
        }

        #pragma unroll
        for (int ks = 0; ks < 4; ks++) {
            bf16x8 v0f = *(const bf16x8*)&Vs[buf][(l32)      * 64 + fgo[ks]];
            bf16x8 v1f = *(const bf16x8*)&Vs[buf][(32 + l32) * 64 + fgo[ks]];
            lsum = __builtin_amdgcn_mfma_f32_32x32x16_bf16(pf[ks], ones, lsum, 0, 0, 0);
            o0   = __builtin_amdgcn_mfma_f32_32x32x16_bf16(pf[ks], v0f, o0, 0, 0, 0);
            o1   = __builtin_amdgcn_mfma_f32_32x32x16_bf16(pf[ks], v1f, o1, 0, 0, 0);
        }
    }

    #pragma unroll
    for (int reg = 0; reg < 16; reg++) {
        float inv = 1.0f / lsum[reg];
        int row = (reg & 3) + 8 * (reg >> 2) + 4 * half;
        int qrow = qt * 128 + wave * 32 + row;
        size_t base = (size_t)(b * 1024 + qrow) * 768 + h * 64 + l32;
        ctx[base]      = f2bf(o0[reg] * inv);
        ctx[base + 32] = f2bf(o1[reg] * inv);
    }
}

// ---------------------------------------------------------------------------
extern "C" void kernel_launch(void* const* d_in, const int* in_sizes, int n_in,
                              void* d_out, int out_size, void* d_ws, size_t ws_size,
                              hipStream_t stream) {
    const float* x      = (const float*)d_in[0];  // [8,1024,768]
    const float* w_qkv  = (const float*)d_in[1];  // [768,2304]
    const float* w_proj = (const float*)d_in[2];  // [768,768]
    const float* b_proj = (const float*)d_in[3];  // [768]
    float* out = (float*)d_out;

    const int BN = 8192;     // B*N
    const int C = 768, C3 = 2304;
    const float CE = 0.18033688011112042f;  // 0.125 * log2(e)

    u16* Xb      = (u16*)d_ws;                       // 8192*768
    u16* Wqkv_t  = Xb + (size_t)BN * C;              // 2304*768
    u16* Wproj_t = Wqkv_t + (size_t)C3 * C;          // 768*768
    u16* QKV     = Wproj_t + (size_t)C * C;          // 8192*2304 (Q,K used)
    u16* Vt      = QKV + (size_t)BN * C3;            // 96*64*1024
    u16* Ctx     = Vt + (size_t)96 * 64 * 1024;      // 8192*768

    static bool s_attr = false;
    if (!s_attr) {
        (void)hipFuncSetAttribute((const void*)gemm_qkv8<768>,
                                  hipFuncAttributeMaxDynamicSharedMemorySize, 131072);
        s_attr = true;
    }

    convert_bf16<<<(BN * C / 4 + 255) / 256, 256, 0, stream>>>(x, Xb, BN * C / 4);
    prep_weights<<<2304, 256, 0, stream>>>(w_qkv, w_proj, Wqkv_t, Wproj_t);

    gemm_qkv8<768><<<288, 512, 131072, stream>>>(Xb, Wqkv_t, QKV, Vt, CE);

    attn_kernel<<<dim3(8, 96), 256, 0, stream>>>(QKV, Vt, Ctx);

    gemm_proj<768><<<dim3(C / 128, BN / 128), 256, 0, stream>>>(
        Ctx, Wproj_t, out, b_proj, BN, C);
}

// Round 2
// 205.637 us; speedup vs baseline: 1.7726x; 1.7726x over previous
//
#include <hip/hip_runtime.h>

typedef __bf16 bf16x8 __attribute__((ext_vector_type(8)));
typedef float f32x4 __attribute__((ext_vector_type(4)));
typedef float f32x16 __attribute__((ext_vector_type(16)));
typedef unsigned short u16;
typedef unsigned int u32;
typedef u16 u16x4 __attribute__((ext_vector_type(4)));
typedef u32 u32x4 __attribute__((ext_vector_type(4)));

__device__ __forceinline__ u16 f2bf(float f) {
    union { float f; u32 u; } x{f};
    u32 r = x.u + 0x7FFFu + ((x.u >> 16) & 1u);  // RNE
    return (u16)(r >> 16);
}

__device__ __forceinline__ float ex2(float x) {
#if __has_builtin(__builtin_amdgcn_exp2f)
    return __builtin_amdgcn_exp2f(x);
#else
    return __expf(x * 0.6931471805599453f);
#endif
}

// round-half-up bf16 (inputs >= 0), packed pair into u32
__device__ __forceinline__ u32 pkbf(float a, float b) {
    union { float f; u32 u; } ca{a}, cb{b};
    return ((ca.u + 0x8000u) >> 16) | (((cb.u + 0x8000u) >> 16) << 16);
}

// async global->LDS, 16B per lane; LDS dest = wave-uniform base + lane*16
#define GLD16(g, l)                                                            \
    __builtin_amdgcn_global_load_lds(                                          \
        (const __attribute__((address_space(1))) u32*)(g),                     \
        (__attribute__((address_space(3))) u32*)(l), 16, 0, 0)

// ---------------------------------------------------------------------------
// Elementwise fp32 -> bf16 convert (x)
// ---------------------------------------------------------------------------
__global__ void convert_bf16(const float* __restrict__ src, u16* __restrict__ dst, int n4) {
    int i = blockIdx.x * blockDim.x + threadIdx.x;
    if (i < n4) {
        float4 f = *(const float4*)(src + (size_t)i * 4);
        u16x4 u = { f2bf(f.x), f2bf(f.y), f2bf(f.z), f2bf(f.w) };
        *(u16x4*)(dst + (size_t)i * 4) = u;
    }
}

// ---------------------------------------------------------------------------
// Both weight transposes in one kernel.
// ---------------------------------------------------------------------------
__global__ __launch_bounds__(256) void prep_weights(
    const float* __restrict__ wq, const float* __restrict__ wp,
    u16* __restrict__ WqT, u16* __restrict__ WpT)
{
    __shared__ u16 tile[32][33];
    int id = blockIdx.x;
    const float* src; u16* dst; int R, C, bx, by;
    if (id < 1728) { src = wq; dst = WqT; R = 768; C = 2304; bx = (id % 72) * 32; by = (id / 72) * 32; }
    else { id -= 1728; src = wp; dst = WpT; R = 768; C = 768; bx = (id % 24) * 32; by = (id / 24) * 32; }
    int x = threadIdx.x & 31, y = threadIdx.x >> 5;
    #pragma unroll
    for (int i = 0; i < 32; i += 8)
        tile[y + i][x] = f2bf(src[(size_t)(by + y + i) * C + bx + x]);
    __syncthreads();
    #pragma unroll
    for (int i = 0; i < 32; i += 8)
        dst[(size_t)(bx + y + i) * R + by + x] = tile[x][y + i];
}

// ---------------------------------------------------------------------------
// QKV GEMM: 128x128 tile, BK=64, XOR-granule swizzle, V-section writes
// Vt[bh][d][n] via operand swap.  R2 change: DOUBLE-BUFFERED LDS + 2-phase
// schedule (T3-minimum): issue next tile's global_load_lds BEFORE computing
// the current buffer, one __syncthreads (vmcnt0+barrier) per K-tile.
// Removes the per-K-step exposed load latency of the single-buffer version.
// ---------------------------------------------------------------------------
template <int K>
__global__ __launch_bounds__(256) void gemm_qkv(
    const u16* __restrict__ A,
    const u16* __restrict__ Wt,
    u16* __restrict__ QKV,
    u16* __restrict__ Vt,
    float qscale)
{
    __shared__ __align__(16) u16 As[2][128 * 64];
    __shared__ __align__(16) u16 Bs[2][128 * 64];

    constexpr int NT = K / 64;          // 12 K-tiles

    int tid = threadIdx.x;
    int wave = tid >> 6, lane = tid & 63;
    int quad = lane >> 4, l16 = lane & 15;
    int wm = (wave >> 1) * 64, wn = (wave & 1) * 64;
    int bm = blockIdx.y * 128, bn = blockIdx.x * 128;
    bool vsec = (bn >= 1536);

    f32x4 acc[4][4] = {};

    int srow = lane >> 3;
    int scg = ((lane & 7) ^ srow) * 8;
    const u16* Ap = A + (size_t)(bm + wave * 32 + srow) * K + scg;
    const u16* Bp = Wt + (size_t)(bn + wave * 32 + srow) * K + scg;

    int fg0 = (((0 * 4 + quad) ^ (l16 & 7)) * 8);
    int fg1 = (((1 * 4 + quad) ^ (l16 & 7)) * 8);

    // prologue: stage tile 0 into buffer 0
    #pragma unroll
    for (int j = 0; j < 4; j++) {
        GLD16(Ap + (size_t)j * 8 * K, &As[0][(wave * 32 + j * 8) * 64]);
        GLD16(Bp + (size_t)j * 8 * K, &Bs[0][(wave * 32 + j * 8) * 64]);
    }
    __syncthreads();    // vmcnt(0) + barrier: buf0 ready

    for (int t = 0; t < NT; ++t) {
        int buf = t & 1;

        // issue next tile's staging into the other buffer FIRST; its latency
        // hides under this tile's LDS reads + MFMAs.
        if (t + 1 < NT) {
            #pragma unroll
            for (int j = 0; j < 4; j++) {
                GLD16(Ap + (t + 1) * 64 + (size_t)j * 8 * K, &As[buf ^ 1][(wave * 32 + j * 8) * 64]);
                GLD16(Bp + (t + 1) * 64 + (size_t)j * 8 * K, &Bs[buf ^ 1][(wave * 32 + j * 8) * 64]);
            }
        }

        #pragma unroll
        for (int h = 0; h < 2; h++) {
            int fg = h ? fg1 : fg0;
            bf16x8 af[4], bfr[4];
            #pragma unroll
            for (int i = 0; i < 4; i++) {
                af[i]  = *(const bf16x8*)&As[buf][(wm + i * 16 + l16) * 64 + fg];
                bfr[i] = *(const bf16x8*)&Bs[buf][(wn + i * 16 + l16) * 64 + fg];
            }
            if (!vsec) {
                #pragma unroll
                for (int mi = 0; mi < 4; mi++)
                    #pragma unroll
                    for (int ni = 0; ni < 4; ni++)
                        acc[mi][ni] = __builtin_amdgcn_mfma_f32_16x16x32_bf16(af[mi], bfr[ni], acc[mi][ni], 0, 0, 0);
            } else {
                #pragma unroll
                for (int mi = 0; mi < 4; mi++)
                    #pragma unroll
                    for (int ni = 0; ni < 4; ni++)
                        acc[mi][ni] = __builtin_amdgcn_mfma_f32_16x16x32_bf16(bfr[ni], af[mi], acc[mi][ni], 0, 0, 0);
            }
        }

        // vmcnt(0)+lgkmcnt(0)+barrier: publishes tile t+1, and all reads of
        // buf are data-consumed above, so buf is safe to overwrite at t+1.
        __syncthreads();
    }

    if (!vsec) {
        #pragma unroll
        for (int mi = 0; mi < 4; mi++) {
            #pragma unroll
            for (int ni = 0; ni < 4; ni++) {
                #pragma unroll
                for (int rg = 0; rg < 4; rg++) {
                    int row = bm + wm + mi * 16 + quad * 4 + rg;
                    int col = bn + wn + ni * 16 + l16;
                    float sc = (col < 768) ? qscale : 1.0f;
                    QKV[(size_t)row * 2304 + col] = f2bf(acc[mi][ni][rg] * sc);
                }
            }
        }
    } else {
        #pragma unroll
        for (int mi = 0; mi < 4; mi++) {
            #pragma unroll
            for (int ni = 0; ni < 4; ni++) {
                #pragma unroll
                for (int rg = 0; rg < 4; rg++) {
                    int d = (bn - 1536) + wn + ni * 16 + quad * 4 + rg;
                    int ng = bm + wm + mi * 16 + l16;
                    int b = ng >> 10, n = ng & 1023, h = d >> 6;
                    Vt[((size_t)(b * 12 + h) * 64 + (d & 63)) * 1024 + n] = f2bf(acc[mi][ni][rg]);
                }
            }
        }
    }
}

// ---------------------------------------------------------------------------
// Output projection GEMM: same 2-phase double-buffered schedule.
// ---------------------------------------------------------------------------
template <int K>
__global__ __launch_bounds__(256) void gemm_proj(
    const u16* __restrict__ A,
    const u16* __restrict__ Bt,
    float* __restrict__ Cp,
    const float* __restrict__ bias,
    int M, int N)
{
    __shared__ __align__(16) u16 As[2][128 * 64];
    __shared__ __align__(16) u16 Bs[2][128 * 64];

    constexpr int NT = K / 64;

    int tid = threadIdx.x;
    int wave = tid >> 6, lane = tid & 63;
    int quad = lane >> 4, l16 = lane & 15;
    int wm = (wave >> 1) * 64, wn = (wave & 1) * 64;
    int bm = blockIdx.y * 128, bn = blockIdx.x * 128;

    f32x4 acc[4][4] = {};

    int srow = lane >> 3;
    int scg = ((lane & 7) ^ srow) * 8;
    const u16* Ap = A + (size_t)(bm + wave * 32 + srow) * K + scg;
    const u16* Bp = Bt + (size_t)(bn + wave * 32 + srow) * K + scg;

    int fg0 = (((0 * 4 + quad) ^ (l16 & 7)) * 8);
    int fg1 = (((1 * 4 + quad) ^ (l16 & 7)) * 8);

    #pragma unroll
    for (int j = 0; j < 4; j++) {
        GLD16(Ap + (size_t)j * 8 * K, &As[0][(wave * 32 + j * 8) * 64]);
        GLD16(Bp + (size_t)j * 8 * K, &Bs[0][(wave * 32 + j * 8) * 64]);
    }
    __syncthreads();

    for (int t = 0; t < NT; ++t) {
        int buf = t & 1;

        if (t + 1 < NT) {
            #pragma unroll
            for (int j = 0; j < 4; j++) {
                GLD16(Ap + (t + 1) * 64 + (size_t)j * 8 * K, &As[buf ^ 1][(wave * 32 + j * 8) * 64]);
                GLD16(Bp + (t + 1) * 64 + (size_t)j * 8 * K, &Bs[buf ^ 1][(wave * 32 + j * 8) * 64]);
            }
        }

        #pragma unroll
        for (int h = 0; h < 2; h++) {
            int fg = h ? fg1 : fg0;
            bf16x8 af[4], bfr[4];
            #pragma unroll
            for (int i = 0; i < 4; i++) {
                af[i]  = *(const bf16x8*)&As[buf][(wm + i * 16 + l16) * 64 + fg];
                bfr[i] = *(const bf16x8*)&Bs[buf][(wn + i * 16 + l16) * 64 + fg];
            }
            #pragma unroll
            for (int mi = 0; mi < 4; mi++)
                #pragma unroll
                for (int ni = 0; ni < 4; ni++)
                    acc[mi][ni] = __builtin_amdgcn_mfma_f32_16x16x32_bf16(af[mi], bfr[ni], acc[mi][ni], 0, 0, 0);
        }

        __syncthreads();
    }

    #pragma unroll
    for (int mi = 0; mi < 4; mi++) {
        #pragma unroll
        for (int ni = 0; ni < 4; ni++) {
            #pragma unroll
            for (int rg = 0; rg < 4; rg++) {
                int row = bm + wm + mi * 16 + quad * 4 + rg;
                int col = bn + wn + ni * 16 + l16;
                Cp[(size_t)row * N + col] = acc[mi][ni][rg] + bias[col];
            }
        }
    }
}

// ---------------------------------------------------------------------------
// Flash attention v4 (unchanged): 32x32x16 MFMA, no P LDS roundtrip.
// ---------------------------------------------------------------------------
__global__ __launch_bounds__(256, 4) void attn_kernel(
    const u16* __restrict__ qkv,
    const u16* __restrict__ Vt,
    u16* __restrict__ ctx)
{
    __shared__ __align__(16) u16 Ks[2][4096];   // 2 x 64key x 64d (swizzled)
    __shared__ __align__(16) u16 Vs[2][4096];   // 2 x 64d x 64key (swizzled)

    int qt = blockIdx.x;            // 0..7 (128 q rows per block)
    int bh = blockIdx.y;            // 0..95
    int b = bh / 12, h = bh % 12;
    int tid = threadIdx.x;
    int wave = tid >> 6, lane = tid & 63;
    int l32 = lane & 31, half = lane >> 5;

    const u16* qbase = qkv + (size_t)(b * 1024 + qt * 128 + wave * 32 + l32) * 2304 + h * 64;
    bf16x8 qa[4];
    #pragma unroll
    for (int ks = 0; ks < 4; ks++)
        qa[ks] = *(const bf16x8*)(qbase + ks * 16 + half * 8);

    int srow = lane >> 3;
    int scol = (lane & 7) ^ srow;
    const u16* kA = qkv + (size_t)(b * 1024 + wave * 16 + srow) * 2304 + 768 + h * 64 + scol * 8;
    const u16* vA = Vt + ((size_t)bh * 64 + wave * 16 + srow) * 1024 + scol * 8;

    bf16x8 ones;
    #pragma unroll
    for (int j = 0; j < 8; j++) ((u16*)&ones)[j] = 0x3F80;  // bf16 1.0

    f32x16 o0 = {}, o1 = {}, lsum = {};

    int fgo[4];
    #pragma unroll
    for (int ks = 0; ks < 4; ks++)
        fgo[ks] = (((ks * 2 + half) ^ (lane & 7)) * 8);

    {
        GLD16(kA,            &Ks[0][(wave * 2 + 0) * 512]);
        GLD16(kA + 8 * 2304, &Ks[0][(wave * 2 + 1) * 512]);
        GLD16(vA,            &Vs[0][(wave * 2 + 0) * 512]);
        GLD16(vA + 8 * 1024, &Vs[0][(wave * 2 + 1) * 512]);
    }

    #pragma unroll 2
    for (int kt = 0; kt < 16; kt++) {
        int buf = kt & 1;
        __syncthreads();   // drains vmcnt(0): buf is populated

        if (kt < 15) {
            const u16* k0 = kA + (size_t)(kt + 1) * (64 * 2304);
            const u16* v0 = vA + (size_t)(kt + 1) * 64;
            GLD16(k0,            &Ks[buf ^ 1][(wave * 2 + 0) * 512]);
            GLD16(k0 + 8 * 2304, &Ks[buf ^ 1][(wave * 2 + 1) * 512]);
            GLD16(v0,            &Vs[buf ^ 1][(wave * 2 + 0) * 512]);
            GLD16(v0 + 8 * 1024, &Vs[buf ^ 1][(wave * 2 + 1) * 512]);
        }

        f32x16 st0 = {}, st1 = {};
        #pragma unroll
        for (int ks = 0; ks < 4; ks++) {
            bf16x8 kf0 = *(const bf16x8*)&Ks[buf][(l32)      * 64 + fgo[ks]];
            bf16x8 kf1 = *(const bf16x8*)&Ks[buf][(32 + l32) * 64 + fgo[ks]];
            st0 = __builtin_amdgcn_mfma_f32_32x32x16_bf16(kf0, qa[ks], st0, 0, 0, 0);
            st1 = __builtin_amdgcn_mfma_f32_32x32x16_bf16(kf1, qa[ks], st1, 0, 0, 0);
        }

        bf16x8 pf[4];
        #pragma unroll
        for (int t = 0; t < 2; t++) {
            u32 pk[8];
            #pragma unroll
            for (int g = 0; g < 4; g++) {
                float p0 = ex2(t ? st1[4 * g + 0] : st0[4 * g + 0]);
                float p1 = ex2(t ? st1[4 * g + 1] : st0[4 * g + 1]);
                float p2 = ex2(t ? st1[4 * g + 2] : st0[4 * g + 2]);
                float p3 = ex2(t ? st1[4 * g + 3] : st0[4 * g + 3]);
                pk[2 * g + 0] = pkbf(p0, p1);
                pk[2 * g + 1] = pkbf(p2, p3);
            }
            u32 rA0 = __shfl_xor(half ? pk[0] : pk[2], 32);
            u32 rA1 = __shfl_xor(half ? pk[1] : pk[3], 32);
            u32 rB0 = __shfl_xor(half ? pk[4] : pk[6], 32);
            u32 rB1 = __shfl_xor(half ? pk[5] : pk[7], 32);
            u32x4 f0 = { half ? rA0 : pk[0], half ? rA1 : pk[1],
                         half ? pk[2] : rA0, half ? pk[3] : rA1 };
            u32x4 f1 = { half ? rB0 : pk[4], half ? rB1 : pk[5],
                         half ? pk[6] : rB0, half ? pk[7] : rB1 };
            union { u32x4 u; bf16x8 b; } c0{f0}, c1{f1};
            pf[2 * t + 0] = c0.b;
            pf[2 * t + 1] = c1.b;
        }

        #pragma unroll
        for (int ks = 0; ks < 4; ks++) {
            bf16x8 v0f = *(const bf16x8*)&Vs[buf][(l32)      * 64 + fgo[ks]];
            bf16x8 v1f = *(const bf16x8*)&Vs[buf][(32 + l32) * 64 + fgo[ks]];
            lsum = __builtin_amdgcn_mfma_f32_32x32x16_bf16(pf[ks], ones, lsum, 0, 0, 0);
            o0   = __builtin_amdgcn_mfma_f32_32x32x16_bf16(pf[ks], v0f, o0, 0, 0, 0);
            o1   = __builtin_amdgcn_mfma_f32_32x32x16_bf16(pf[ks], v1f, o1, 0, 0, 0);
        }
    }

    #pragma unroll
    for (int reg = 0; reg < 16; reg++) {
        float inv = 1.0f / lsum[reg];
        int row = (reg & 3) + 8 * (reg >> 2) + 4 * half;
        int qrow = qt * 128 + wave * 32 + row;
        size_t base = (size_t)(b * 1024 + qrow) * 768 + h * 64 + l32;
        ctx[base]      = f2bf(o0[reg] * inv);
        ctx[base + 32] = f2bf(o1[reg] * inv);
    }
}

// ---------------------------------------------------------------------------
extern "C" void kernel_launch(void* const* d_in, const int* in_sizes, int n_in,
                              void* d_out, int out_size, void* d_ws, size_t ws_size,
                              hipStream_t stream) {
    const float* x      = (const float*)d_in[0];  // [8,1024,768]
    const float* w_qkv  = (const float*)d_in[1];  // [768,2304]
    const float* w_proj = (const float*)d_in[2];  // [768,768]
    const float* b_proj = (const float*)d_in[3];  // [768]
    float* out = (float*)d_out;

    const int BN = 8192;     // B*N
    const int C = 768, C3 = 2304;
    const float CE = 0.18033688011112042f;  // 0.125 * log2(e)

    u16* Xb      = (u16*)d_ws;                       // 8192*768
    u16* Wqkv_t  = Xb + (size_t)BN * C;              // 2304*768
    u16* Wproj_t = Wqkv_t + (size_t)C3 * C;          // 768*768
    u16* QKV     = Wproj_t + (size_t)C * C;          // 8192*2304 (Q,K used)
    u16* Vt      = QKV + (size_t)BN * C3;            // 96*64*1024
    u16* Ctx     = Vt + (size_t)96 * 64 * 1024;      // 8192*768

    convert_bf16<<<(BN * C / 4 + 255) / 256, 256, 0, stream>>>(x, Xb, BN * C / 4);
    prep_weights<<<2304, 256, 0, stream>>>(w_qkv, w_proj, Wqkv_t, Wproj_t);

    gemm_qkv<768><<<dim3(C3 / 128, BN / 128), 256, 0, stream>>>(
        Xb, Wqkv_t, QKV, Vt, CE);

    attn_kernel<<<dim3(8, 96), 256, 0, stream>>>(QKV, Vt, Ctx);

    gemm_proj<768><<<dim3(C / 128, BN / 128), 256, 0, stream>>>(
        Ctx, Wproj_t, out, b_proj, BN, C);
}

// Round 3
// 193.571 us; speedup vs baseline: 1.8831x; 1.0623x over previous
//
#include <hip/hip_runtime.h>

typedef __bf16 bf16x8 __attribute__((ext_vector_type(8)));
typedef float f32x4 __attribute__((ext_vector_type(4)));
typedef float f32x16 __attribute__((ext_vector_type(16)));
typedef unsigned short u16;
typedef unsigned int u32;
typedef u16 u16x4 __attribute__((ext_vector_type(4)));
typedef u32 u32x4 __attribute__((ext_vector_type(4)));

__device__ __forceinline__ u16 f2bf(float f) {
    union { float f; u32 u; } x{f};
    u32 r = x.u + 0x7FFFu + ((x.u >> 16) & 1u);  // RNE
    return (u16)(r >> 16);
}

__device__ __forceinline__ float ex2(float x) {
#if __has_builtin(__builtin_amdgcn_exp2f)
    return __builtin_amdgcn_exp2f(x);
#else
    return __expf(x * 0.6931471805599453f);
#endif
}

// round-half-up bf16 (inputs >= 0), packed pair into u32
__device__ __forceinline__ u32 pkbf(float a, float b) {
    union { float f; u32 u; } ca{a}, cb{b};
    return ((ca.u + 0x8000u) >> 16) | (((cb.u + 0x8000u) >> 16) << 16);
}

// async global->LDS, 16B per lane; LDS dest = wave-uniform base + lane*16
#define GLD16(g, l)                                                            \
    __builtin_amdgcn_global_load_lds(                                          \
        (const __attribute__((address_space(1))) u32*)(g),                     \
        (__attribute__((address_space(3))) u32*)(l), 16, 0, 0)

// ---------------------------------------------------------------------------
// Elementwise fp32 -> bf16 convert (x)
// ---------------------------------------------------------------------------
__global__ void convert_bf16(const float* __restrict__ src, u16* __restrict__ dst, int n4) {
    int i = blockIdx.x * blockDim.x + threadIdx.x;
    if (i < n4) {
        float4 f = *(const float4*)(src + (size_t)i * 4);
        u16x4 u = { f2bf(f.x), f2bf(f.y), f2bf(f.z), f2bf(f.w) };
        *(u16x4*)(dst + (size_t)i * 4) = u;
    }
}

// ---------------------------------------------------------------------------
// Both weight transposes in one kernel.
// ---------------------------------------------------------------------------
__global__ __launch_bounds__(256) void prep_weights(
    const float* __restrict__ wq, const float* __restrict__ wp,
    u16* __restrict__ WqT, u16* __restrict__ WpT)
{
    __shared__ u16 tile[32][33];
    int id = blockIdx.x;
    const float* src; u16* dst; int R, C, bx, by;
    if (id < 1728) { src = wq; dst = WqT; R = 768; C = 2304; bx = (id % 72) * 32; by = (id / 72) * 32; }
    else { id -= 1728; src = wp; dst = WpT; R = 768; C = 768; bx = (id % 24) * 32; by = (id / 24) * 32; }
    int x = threadIdx.x & 31, y = threadIdx.x >> 5;
    #pragma unroll
    for (int i = 0; i < 32; i += 8)
        tile[y + i][x] = f2bf(src[(size_t)(by + y + i) * C + bx + x]);
    __syncthreads();
    #pragma unroll
    for (int i = 0; i < 32; i += 8)
        dst[(size_t)(bx + y + i) * R + by + x] = tile[x][y + i];
}

// ---------------------------------------------------------------------------
// QKV GEMM, R3: 128x128 tile, 512 threads / 8 waves (per-wave 32x64 C),
// 3-buffer LDS pipeline (96 KiB), 2 phases per K-tile, raw s_barrier +
// COUNTED s_waitcnt vmcnt(4) per K-tile (never 0 in steady state), setprio
// around MFMA clusters. Staging for tile t+2 is split across the phases of
// tile t, so 4 loads/thread stay in flight across every barrier (T3+T4+T5).
// Per-phase live set: 6 frags + acc[2][4] -> no spill (R1 lesson).
// XOR-granule swizzle identical to the verified R0 kernel. Grid is flat
// 1152 with bijective XCD-chunk swizzle (1152 % 8 == 0): each XCD owns a
// contiguous lin-range -> A-panels + whole 3.5 MB weight L2-resident.
// V-section (bn>=1536) swaps MFMA operands and scatters to Vt (unchanged).
// ---------------------------------------------------------------------------
#define MM8(A0_, A1_, B0_, B1_, B2_, B3_)                                       \
    if (!vsec) {                                                                \
        acc[0][0] = __builtin_amdgcn_mfma_f32_16x16x32_bf16(A0_, B0_, acc[0][0], 0, 0, 0); \
        acc[0][1] = __builtin_amdgcn_mfma_f32_16x16x32_bf16(A0_, B1_, acc[0][1], 0, 0, 0); \
        acc[0][2] = __builtin_amdgcn_mfma_f32_16x16x32_bf16(A0_, B2_, acc[0][2], 0, 0, 0); \
        acc[0][3] = __builtin_amdgcn_mfma_f32_16x16x32_bf16(A0_, B3_, acc[0][3], 0, 0, 0); \
        acc[1][0] = __builtin_amdgcn_mfma_f32_16x16x32_bf16(A1_, B0_, acc[1][0], 0, 0, 0); \
        acc[1][1] = __builtin_amdgcn_mfma_f32_16x16x32_bf16(A1_, B1_, acc[1][1], 0, 0, 0); \
        acc[1][2] = __builtin_amdgcn_mfma_f32_16x16x32_bf16(A1_, B2_, acc[1][2], 0, 0, 0); \
        acc[1][3] = __builtin_amdgcn_mfma_f32_16x16x32_bf16(A1_, B3_, acc[1][3], 0, 0, 0); \
    } else {                                                                    \
        acc[0][0] = __builtin_amdgcn_mfma_f32_16x16x32_bf16(B0_, A0_, acc[0][0], 0, 0, 0); \
        acc[0][1] = __builtin_amdgcn_mfma_f32_16x16x32_bf16(B1_, A0_, acc[0][1], 0, 0, 0); \
        acc[0][2] = __builtin_amdgcn_mfma_f32_16x16x32_bf16(B2_, A0_, acc[0][2], 0, 0, 0); \
        acc[0][3] = __builtin_amdgcn_mfma_f32_16x16x32_bf16(B3_, A0_, acc[0][3], 0, 0, 0); \
        acc[1][0] = __builtin_amdgcn_mfma_f32_16x16x32_bf16(B0_, A1_, acc[1][0], 0, 0, 0); \
        acc[1][1] = __builtin_amdgcn_mfma_f32_16x16x32_bf16(B1_, A1_, acc[1][1], 0, 0, 0); \
        acc[1][2] = __builtin_amdgcn_mfma_f32_16x16x32_bf16(B2_, A1_, acc[1][2], 0, 0, 0); \
        acc[1][3] = __builtin_amdgcn_mfma_f32_16x16x32_bf16(B3_, A1_, acc[1][3], 0, 0, 0); \
    }

#define STG_A(t, j) GLD16(Ap + (t) * 64 + (size_t)(j) * 8 * K,                  \
                          &Asb[((t) % 3) * 8192 + (wave * 16 + (j) * 8) * 64])
#define STG_B(t, j) GLD16(Bp + (t) * 64 + (size_t)(j) * 8 * K,                  \
                          &Bsb[((t) % 3) * 8192 + (wave * 16 + (j) * 8) * 64])

template <int K>
__global__ __launch_bounds__(512, 2) void gemm_qkv(
    const u16* __restrict__ A,
    const u16* __restrict__ Wt,
    u16* __restrict__ QKV,
    u16* __restrict__ Vt,
    float qscale)
{
    extern __shared__ __align__(16) u16 lds[];   // 3*(16K+16K) = 96 KiB
    u16* Asb = lds;              // 3 x 8192 u16
    u16* Bsb = lds + 3 * 8192;   // 3 x 8192 u16

    constexpr int NT = K / 64;   // 12 K-tiles

    int tid = threadIdx.x;
    int wave = tid >> 6, lane = tid & 63;
    int quad = lane >> 4, l16 = lane & 15;
    int wm = (wave >> 1) * 32, wn = (wave & 1) * 64;

    int id = blockIdx.x;
    int lin = (id & 7) * 144 + (id >> 3);   // XCD-chunked, bijective
    int bm = (lin / 18) * 128;
    int bn = (lin % 18) * 128;
    bool vsec = (bn >= 1536);

    f32x4 acc[2][4] = {};

    int srow = lane >> 3;
    int scg = ((lane & 7) ^ srow) * 8;
    const u16* Ap = A  + (size_t)(bm + wave * 16 + srow) * K + scg;
    const u16* Bp = Wt + (size_t)(bn + wave * 16 + srow) * K + scg;

    int fg0 = ((0 * 4 + quad) ^ (l16 & 7)) * 8;
    int fg1 = ((1 * 4 + quad) ^ (l16 & 7)) * 8;

    // prologue: stage tiles 0 and 1 (8 loads); wait tile 0 (4 stay in flight)
    STG_A(0, 0); STG_A(0, 1); STG_B(0, 0); STG_B(0, 1);
    STG_A(1, 0); STG_A(1, 1); STG_B(1, 0); STG_B(1, 1);
    asm volatile("s_waitcnt vmcnt(4)" ::: "memory");
    __builtin_amdgcn_s_barrier();

    #pragma unroll
    for (int t = 0; t < NT; ++t) {
        const u16* Ab = &Asb[(t % 3) * 8192];
        const u16* Bb = &Bsb[(t % 3) * 8192];

        // ---- phase 0 (k-half 0): read frags, stage A(t+2), MFMA ----
        {
            bf16x8 a0 = *(const bf16x8*)&Ab[(wm +  0 + l16) * 64 + fg0];
            bf16x8 a1 = *(const bf16x8*)&Ab[(wm + 16 + l16) * 64 + fg0];
            bf16x8 b0 = *(const bf16x8*)&Bb[(wn +  0 + l16) * 64 + fg0];
            bf16x8 b1 = *(const bf16x8*)&Bb[(wn + 16 + l16) * 64 + fg0];
            bf16x8 b2 = *(const bf16x8*)&Bb[(wn + 32 + l16) * 64 + fg0];
            bf16x8 b3 = *(const bf16x8*)&Bb[(wn + 48 + l16) * 64 + fg0];
            if (t + 2 < NT) { STG_A(t + 2, 0); STG_A(t + 2, 1); }
            __builtin_amdgcn_s_barrier();
            __builtin_amdgcn_s_setprio(1);
            MM8(a0, a1, b0, b1, b2, b3);
            __builtin_amdgcn_s_setprio(0);
            __builtin_amdgcn_s_barrier();
        }

        // ---- phase 1 (k-half 1): read frags, stage B(t+2), MFMA, counted wait ----
        {
            bf16x8 a0 = *(const bf16x8*)&Ab[(wm +  0 + l16) * 64 + fg1];
            bf16x8 a1 = *(const bf16x8*)&Ab[(wm + 16 + l16) * 64 + fg1];
            bf16x8 b0 = *(const bf16x8*)&Bb[(wn +  0 + l16) * 64 + fg1];
            bf16x8 b1 = *(const bf16x8*)&Bb[(wn + 16 + l16) * 64 + fg1];
            bf16x8 b2 = *(const bf16x8*)&Bb[(wn + 32 + l16) * 64 + fg1];
            bf16x8 b3 = *(const bf16x8*)&Bb[(wn + 48 + l16) * 64 + fg1];
            if (t + 2 < NT) { STG_B(t + 2, 0); STG_B(t + 2, 1); }
            __builtin_amdgcn_s_barrier();
            __builtin_amdgcn_s_setprio(1);
            MM8(a0, a1, b0, b1, b2, b3);
            __builtin_amdgcn_s_setprio(0);
            // end-of-tile wait: t+1's 4 loads must be done; t+2's 4 stay in flight
            if (t + 2 < NT)      { asm volatile("s_waitcnt vmcnt(4)" ::: "memory"); }
            else if (t + 1 < NT) { asm volatile("s_waitcnt vmcnt(0)" ::: "memory"); }
            __builtin_amdgcn_s_barrier();
        }
    }

    if (!vsec) {
        float sc = (bn < 768) ? qscale : 1.0f;   // col-tile is uniformly Q or K
        #pragma unroll
        for (int mi = 0; mi < 2; mi++) {
            #pragma unroll
            for (int ni = 0; ni < 4; ni++) {
                #pragma unroll
                for (int rg = 0; rg < 4; rg++) {
                    int row = bm + wm + mi * 16 + quad * 4 + rg;
                    int col = bn + wn + ni * 16 + l16;
                    QKV[(size_t)row * 2304 + col] = f2bf(acc[mi][ni][rg] * sc);
                }
            }
        }
    } else {
        #pragma unroll
        for (int mi = 0; mi < 2; mi++) {
            #pragma unroll
            for (int ni = 0; ni < 4; ni++) {
                #pragma unroll
                for (int rg = 0; rg < 4; rg++) {
                    int d = (bn - 1536) + wn + ni * 16 + quad * 4 + rg;
                    int ng = bm + wm + mi * 16 + l16;
                    int b = ng >> 10, n = ng & 1023, h = d >> 6;
                    Vt[((size_t)(b * 12 + h) * 64 + (d & 63)) * 1024 + n] = f2bf(acc[mi][ni][rg]);
                }
            }
        }
    }
}

#undef MM8
#undef STG_A
#undef STG_B

// ---------------------------------------------------------------------------
// Output projection GEMM (reverted to R0 single-buffer: dbuf cost ~10 us).
// ---------------------------------------------------------------------------
template <int K>
__global__ __launch_bounds__(256) void gemm_proj(
    const u16* __restrict__ A,
    const u16* __restrict__ Bt,
    float* __restrict__ Cp,
    const float* __restrict__ bias,
    int M, int N)
{
    __shared__ __align__(16) u16 As[128 * 64];
    __shared__ __align__(16) u16 Bs[128 * 64];

    int tid = threadIdx.x;
    int wave = tid >> 6, lane = tid & 63;
    int quad = lane >> 4, l16 = lane & 15;
    int wm = (wave >> 1) * 64, wn = (wave & 1) * 64;
    int bm = blockIdx.y * 128, bn = blockIdx.x * 128;

    f32x4 acc[4][4] = {};

    int srow = lane >> 3;
    int scg = ((lane & 7) ^ srow) * 8;
    const u16* Ap = A + (size_t)(bm + wave * 32 + srow) * K + scg;
    const u16* Bp = Bt + (size_t)(bn + wave * 32 + srow) * K + scg;

    int fg0 = (((0 * 4 + quad) ^ (l16 & 7)) * 8);
    int fg1 = (((1 * 4 + quad) ^ (l16 & 7)) * 8);

    for (int k0 = 0; k0 < K; k0 += 64) {
        #pragma unroll
        for (int j = 0; j < 4; j++) {
            GLD16(Ap + k0 + (size_t)j * 8 * K, &As[(wave * 32 + j * 8) * 64]);
            GLD16(Bp + k0 + (size_t)j * 8 * K, &Bs[(wave * 32 + j * 8) * 64]);
        }
        __syncthreads();

        #pragma unroll
        for (int h = 0; h < 2; h++) {
            int fg = h ? fg1 : fg0;
            bf16x8 af[4], bfr[4];
            #pragma unroll
            for (int i = 0; i < 4; i++) {
                af[i]  = *(const bf16x8*)&As[(wm + i * 16 + l16) * 64 + fg];
                bfr[i] = *(const bf16x8*)&Bs[(wn + i * 16 + l16) * 64 + fg];
            }
            #pragma unroll
            for (int mi = 0; mi < 4; mi++)
                #pragma unroll
                for (int ni = 0; ni < 4; ni++)
                    acc[mi][ni] = __builtin_amdgcn_mfma_f32_16x16x32_bf16(af[mi], bfr[ni], acc[mi][ni], 0, 0, 0);
        }
        __syncthreads();
    }

    #pragma unroll
    for (int mi = 0; mi < 4; mi++) {
        #pragma unroll
        for (int ni = 0; ni < 4; ni++) {
            #pragma unroll
            for (int rg = 0; rg < 4; rg++) {
                int row = bm + wm + mi * 16 + quad * 4 + rg;
                int col = bn + wn + ni * 16 + l16;
                Cp[(size_t)row * N + col] = acc[mi][ni][rg] + bias[col];
            }
        }
    }
}

// ---------------------------------------------------------------------------
// Flash attention v4 (unchanged): 32x32x16 MFMA, no P LDS roundtrip.
// ---------------------------------------------------------------------------
__global__ __launch_bounds__(256, 4) void attn_kernel(
    const u16* __restrict__ qkv,
    const u16* __restrict__ Vt,
    u16* __restrict__ ctx)
{
    __shared__ __align__(16) u16 Ks[2][4096];   // 2 x 64key x 64d (swizzled)
    __shared__ __align__(16) u16 Vs[2][4096];   // 2 x 64d x 64key (swizzled)

    int qt = blockIdx.x;            // 0..7 (128 q rows per block)
    int bh = blockIdx.y;            // 0..95
    int b = bh / 12, h = bh % 12;
    int tid = threadIdx.x;
    int wave = tid >> 6, lane = tid & 63;
    int l32 = lane & 31, half = lane >> 5;

    const u16* qbase = qkv + (size_t)(b * 1024 + qt * 128 + wave * 32 + l32) * 2304 + h * 64;
    bf16x8 qa[4];
    #pragma unroll
    for (int ks = 0; ks < 4; ks++)
        qa[ks] = *(const bf16x8*)(qbase + ks * 16 + half * 8);

    int srow = lane >> 3;
    int scol = (lane & 7) ^ srow;
    const u16* kA = qkv + (size_t)(b * 1024 + wave * 16 + srow) * 2304 + 768 + h * 64 + scol * 8;
    const u16* vA = Vt + ((size_t)bh * 64 + wave * 16 + srow) * 1024 + scol * 8;

    bf16x8 ones;
    #pragma unroll
    for (int j = 0; j < 8; j++) ((u16*)&ones)[j] = 0x3F80;  // bf16 1.0

    f32x16 o0 = {}, o1 = {}, lsum = {};

    int fgo[4];
    #pragma unroll
    for (int ks = 0; ks < 4; ks++)
        fgo[ks] = (((ks * 2 + half) ^ (lane & 7)) * 8);

    {
        GLD16(kA,            &Ks[0][(wave * 2 + 0) * 512]);
        GLD16(kA + 8 * 2304, &Ks[0][(wave * 2 + 1) * 512]);
        GLD16(vA,            &Vs[0][(wave * 2 + 0) * 512]);
        GLD16(vA + 8 * 1024, &Vs[0][(wave * 2 + 1) * 512]);
    }

    #pragma unroll 2
    for (int kt = 0; kt < 16; kt++) {
        int buf = kt & 1;
        __syncthreads();   // drains vmcnt(0): buf is populated

        if (kt < 15) {
            const u16* k0 = kA + (size_t)(kt + 1) * (64 * 2304);
            const u16* v0 = vA + (size_t)(kt + 1) * 64;
            GLD16(k0,            &Ks[buf ^ 1][(wave * 2 + 0) * 512]);
            GLD16(k0 + 8 * 2304, &Ks[buf ^ 1][(wave * 2 + 1) * 512]);
            GLD16(v0,            &Vs[buf ^ 1][(wave * 2 + 0) * 512]);
            GLD16(v0 + 8 * 1024, &Vs[buf ^ 1][(wave * 2 + 1) * 512]);
        }

        f32x16 st0 = {}, st1 = {};
        #pragma unroll
        for (int ks = 0; ks < 4; ks++) {
            bf16x8 kf0 = *(const bf16x8*)&Ks[buf][(l32)      * 64 + fgo[ks]];
            bf16x8 kf1 = *(const bf16x8*)&Ks[buf][(32 + l32) * 64 + fgo[ks]];
            st0 = __builtin_amdgcn_mfma_f32_32x32x16_bf16(kf0, qa[ks], st0, 0, 0, 0);
            st1 = __builtin_amdgcn_mfma_f32_32x32x16_bf16(kf1, qa[ks], st1, 0, 0, 0);
        }

        bf16x8 pf[4];
        #pragma unroll
        for (int t = 0; t < 2; t++) {
            u32 pk[8];
            #pragma unroll
            for (int g = 0; g < 4; g++) {
                float p0 = ex2(t ? st1[4 * g + 0] : st0[4 * g + 0]);
                float p1 = ex2(t ? st1[4 * g + 1] : st0[4 * g + 1]);
                float p2 = ex2(t ? st1[4 * g + 2] : st0[4 * g + 2]);
                float p3 = ex2(t ? st1[4 * g + 3] : st0[4 * g + 3]);
                pk[2 * g + 0] = pkbf(p0, p1);
                pk[2 * g + 1] = pkbf(p2, p3);
            }
            u32 rA0 = __shfl_xor(half ? pk[0] : pk[2], 32);
            u32 rA1 = __shfl_xor(half ? pk[1] : pk[3], 32);
            u32 rB0 = __shfl_xor(half ? pk[4] : pk[6], 32);
            u32 rB1 = __shfl_xor(half ? pk[5] : pk[7], 32);
            u32x4 f0 = { half ? rA0 : pk[0], half ? rA1 : pk[1],
                         half ? pk[2] : rA0, half ? pk[3] : rA1 };
            u32x4 f1 = { half ? rB0 : pk[4], half ? rB1 : pk[5],
                         half ? pk[6] : rB0, half ? pk[7] : rB1 };
            union { u32x4 u; bf16x8 b; } c0{f0}, c1{f1};
            pf[2 * t + 0] = c0.b;
            pf[2 * t + 1] = c1.b;
        }

        #pragma unroll
        for (int ks = 0; ks < 4; ks++) {
            bf16x8 v0f = *(const bf16x8*)&Vs[buf][(l32)      * 64 + fgo[ks]];
            bf16x8 v1f = *(const bf16x8*)&Vs[buf][(32 + l32) * 64 + fgo[ks]];
            lsum = __builtin_amdgcn_mfma_f32_32x32x16_bf16(pf[ks], ones, lsum, 0, 0, 0);
            o0   = __builtin_amdgcn_mfma_f32_32x32x16_bf16(pf[ks], v0f, o0, 0, 0, 0);
            o1   = __builtin_amdgcn_mfma_f32_32x32x16_bf16(pf[ks], v1f, o1, 0, 0, 0);
        }
    }

    #pragma unroll
    for (int reg = 0; reg < 16; reg++) {
        float inv = 1.0f / lsum[reg];
        int row = (reg & 3) + 8 * (reg >> 2) + 4 * half;
        int qrow = qt * 128 + wave * 32 + row;
        size_t base = (size_t)(b * 1024 + qrow) * 768 + h * 64 + l32;
        ctx[base]      = f2bf(o0[reg] * inv);
        ctx[base + 32] = f2bf(o1[reg] * inv);
    }
}

// ---------------------------------------------------------------------------
extern "C" void kernel_launch(void* const* d_in, const int* in_sizes, int n_in,
                              void* d_out, int out_size, void* d_ws, size_t ws_size,
                              hipStream_t stream) {
    const float* x      = (const float*)d_in[0];  // [8,1024,768]
    const float* w_qkv  = (const float*)d_in[1];  // [768,2304]
    const float* w_proj = (const float*)d_in[2];  // [768,768]
    const float* b_proj = (const float*)d_in[3];  // [768]
    float* out = (float*)d_out;

    const int BN = 8192;     // B*N
    const int C = 768, C3 = 2304;
    const float CE = 0.18033688011112042f;  // 0.125 * log2(e)

    u16* Xb      = (u16*)d_ws;                       // 8192*768
    u16* Wqkv_t  = Xb + (size_t)BN * C;              // 2304*768
    u16* Wproj_t = Wqkv_t + (size_t)C3 * C;          // 768*768
    u16* QKV     = Wproj_t + (size_t)C * C;          // 8192*2304 (Q,K used)
    u16* Vt      = QKV + (size_t)BN * C3;            // 96*64*1024
    u16* Ctx     = Vt + (size_t)96 * 64 * 1024;      // 8192*768

    static bool s_attr = false;
    if (!s_attr) {
        (void)hipFuncSetAttribute((const void*)gemm_qkv<768>,
                                  hipFuncAttributeMaxDynamicSharedMemorySize, 98304);
        s_attr = true;
    }

    convert_bf16<<<(BN * C / 4 + 255) / 256, 256, 0, stream>>>(x, Xb, BN * C / 4);
    prep_weights<<<2304, 256, 0, stream>>>(w_qkv, w_proj, Wqkv_t, Wproj_t);

    gemm_qkv<768><<<1152, 512, 98304, stream>>>(Xb, Wqkv_t, QKV, Vt, CE);

    attn_kernel<<<dim3(8, 96), 256, 0, stream>>>(QKV, Vt, Ctx);

    gemm_proj<768><<<dim3(C / 128, BN / 128), 256, 0, stream>>>(
        Ctx, Wproj_t, out, b_proj, BN, C);
}